// Round 4
// baseline (148.005 us; speedup 1.0000x reference)
//
#include <hip/hip_runtime.h>

#define IMG 224
#define HW (IMG * IMG)
#define HW4 (HW / 4)
#define NB 128
#define NPTS 16384

// ---- ws layout ----
// [0, NB*NPTS*3) floats : packed (px, py, rz) per point
// then 128 uint minkeys, 128 uint maxkeys (order-preserving float keys)
#define PACKED_FLOATS ((size_t)NB * NPTS * 3)
#define MINKEY_BYTE_OFF (PACKED_FLOATS * sizeof(float))

// order-preserving float<->uint key (ascending)
__device__ __forceinline__ unsigned fkey(float f) {
    unsigned u = __float_as_uint(f);
    return (u & 0x80000000u) ? ~u : (u | 0x80000000u);
}
__device__ __forceinline__ float fdec(unsigned k) {
    unsigned u = (k & 0x80000000u) ? (k & 0x7FFFFFFFu) : ~k;
    return __uint_as_float(u);
}

// ---------------------------------------------------------------------------
// Kernel 1: stream-transform every point once. Grid = NB*8 blocks x 256 thr.
// Block (b, chunk) handles 2048 points of batch b: writes packed (px,py,rz)
// and contributes to per-batch z min/max via 2 device atomics on uint keys.
// blockIdx = chunk*NB + b so batch b always lands on XCD b%8 (L2 locality
// with k_splat, which uses the same mapping).
// ---------------------------------------------------------------------------
__global__ __launch_bounds__(256) void k_prep(const float* __restrict__ pts,
                                              const float* __restrict__ az,
                                              const float* __restrict__ el,
                                              float* __restrict__ packed,
                                              unsigned* __restrict__ minkeys,
                                              unsigned* __restrict__ maxkeys) {
    const int b = blockIdx.x & (NB - 1);
    const int chunk = blockIdx.x >> 7;     // 0..7

    float sa, ca, se, ce;
    __sincosf(az[b], &sa, &ca);
    __sincosf(el[b], &se, &ce);
    const float r00 = ca,       r02 = sa;
    const float r10 = se * sa,  r11 = ce,  r12 = -se * ca;
    const float r20 = -ce * sa, r21 = se,  r22 = ce * ca;

    const float4* __restrict__ pb4 = (const float4*)(pts + (size_t)b * NPTS * 3);
    float4* __restrict__ pk4 = (float4*)(packed + (size_t)b * NPTS * 3);

    float zmin = 1e30f, zmax = -1e30f;

    auto xform = [&](float x, float y, float z, float& px, float& py, float& rz) {
        const float rx = r00 * x + r02 * z;
        const float ry = r10 * x + r11 * y + r12 * z;
        rz = r20 * x + r21 * y + r22 * z;
        px = (rx + 1.0f) * (0.5f * IMG) - 0.5f;
        py = (ry + 1.0f) * (0.5f * IMG) - 0.5f;
        zmin = fminf(zmin, rz);
        zmax = fmaxf(zmax, rz);
    };

#pragma unroll
    for (int it = 0; it < 2; ++it) {
        const int t = chunk * 512 + it * 256 + threadIdx.x;   // 4-point group
        const float4 v0 = pb4[3 * t + 0];
        const float4 v1 = pb4[3 * t + 1];
        const float4 v2 = pb4[3 * t + 2];
        float px0, py0, rz0, px1, py1, rz1, px2, py2, rz2, px3, py3, rz3;
        xform(v0.x, v0.y, v0.z, px0, py0, rz0);
        xform(v0.w, v1.x, v1.y, px1, py1, rz1);
        xform(v1.z, v1.w, v2.x, px2, py2, rz2);
        xform(v2.y, v2.z, v2.w, px3, py3, rz3);
        pk4[3 * t + 0] = make_float4(px0, py0, rz0, px1);
        pk4[3 * t + 1] = make_float4(py1, rz1, px2, py2);
        pk4[3 * t + 2] = make_float4(rz2, px3, py3, rz3);
    }

    // wave reduce
    for (int m = 1; m < 64; m <<= 1) {
        zmin = fminf(zmin, __shfl_xor(zmin, m));
        zmax = fmaxf(zmax, __shfl_xor(zmax, m));
    }
    __shared__ float wmin[4], wmax[4];
    const int wid = threadIdx.x >> 6;
    if ((threadIdx.x & 63) == 0) { wmin[wid] = zmin; wmax[wid] = zmax; }
    __syncthreads();
    if (threadIdx.x == 0) {
        zmin = fminf(fminf(wmin[0], wmin[1]), fminf(wmin[2], wmin[3]));
        zmax = fmaxf(fmaxf(wmax[0], wmax[1]), fmaxf(wmax[2], wmax[3]));
        atomicMin(&minkeys[b], fkey(zmin));
        atomicMax(&maxkeys[b], fkey(zmax));
    }
}

// ---------------------------------------------------------------------------
// Kernel 2: splat from packed buffer. Grid = NB*8 blocks x 512 thr.
// Block (b, g) owns rows [g*28, g*28+28); 25 KB LDS tile -> 4 blocks/CU
// resident (full 2048-thread occupancy). Packed reads are L2-hot.
// ---------------------------------------------------------------------------
#define GROUPS 8
#define RPB (IMG / GROUPS)            // 28
#define TILE_FLOATS (RPB * IMG)       // 6272 floats = 25088 B
#define BTHREADS 512

__global__ __launch_bounds__(BTHREADS) void k_splat(const float* __restrict__ packed,
                                                    const unsigned* __restrict__ minkeys,
                                                    const unsigned* __restrict__ maxkeys,
                                                    float* __restrict__ out) {
    const int b = blockIdx.x & (NB - 1);
    const int g = blockIdx.x >> 7;
    const int y0 = g * RPB;

    __shared__ float tile[TILE_FLOATS];
    for (int i = threadIdx.x; i < TILE_FLOATS; i += BTHREADS) tile[i] = 0.0f;

    const float zmin = fdec(minkeys[b]);
    const float zmax = fdec(maxkeys[b]);
    const float inv = 0.7f / (zmax - zmin + 1e-6f);
    __syncthreads();

    const float4* __restrict__ pk4 = (const float4*)(packed + (size_t)b * NPTS * 3);

    auto splat = [&](float px, float py, float rz) {
        const float px1 = floorf(px);
        const float py1 = floorf(py);
        if (px1 >= 0.0f && py1 >= 0.0f && px1 < (float)(IMG - 1) && py1 < (float)(IMG - 1)) {
            const float feat = 0.3f + (rz - zmin) * inv;
            const float wx2 = px - px1;
            const float wx1 = 1.0f - wx2;
            const float wy2 = py - py1;
            const float wy1 = 1.0f - wy2;
            const int ix = (int)px1;
            const int iy = (int)py1;
            const int r0 = iy - y0;
            const int r1 = r0 + 1;
            if (r0 >= 0 && r0 < RPB) {
                atomicAdd(&tile[r0 * IMG + ix],     wx1 * wy1 * feat);
                atomicAdd(&tile[r0 * IMG + ix + 1], wx2 * wy1 * feat);
            }
            if (r1 >= 0 && r1 < RPB) {
                atomicAdd(&tile[r1 * IMG + ix],     wx1 * wy2 * feat);
                atomicAdd(&tile[r1 * IMG + ix + 1], wx2 * wy2 * feat);
            }
        }
    };

#pragma unroll
    for (int it = 0; it < NPTS / 4 / BTHREADS; ++it) {   // 8 iterations
        const int t = it * BTHREADS + threadIdx.x;
        const float4 w0 = pk4[3 * t + 0];
        const float4 w1 = pk4[3 * t + 1];
        const float4 w2 = pk4[3 * t + 2];
        splat(w0.x, w0.y, w0.z);
        splat(w0.w, w1.x, w1.y);
        splat(w1.z, w1.w, w2.x);
        splat(w2.y, w2.z, w2.w);
    }

    __syncthreads();

    // exclusive region -> 3 broadcast channels
    const float4* __restrict__ t4 = (const float4*)tile;
    float4* __restrict__ o4 = (float4*)(out + (size_t)b * 3 * HW + (size_t)y0 * IMG);
    for (int i = threadIdx.x; i < TILE_FLOATS / 4; i += BTHREADS) {
        const float4 v = t4[i];
        o4[i] = v;
        o4[i + HW4] = v;
        o4[i + 2 * HW4] = v;
    }
}

extern "C" void kernel_launch(void* const* d_in, const int* in_sizes, int n_in,
                              void* d_out, int out_size, void* d_ws, size_t ws_size,
                              hipStream_t stream) {
    const float* pts = (const float*)d_in[0];
    const float* az  = (const float*)d_in[1];
    const float* el  = (const float*)d_in[2];
    float* out = (float*)d_out;

    float* packed = (float*)d_ws;
    unsigned* minkeys = (unsigned*)((char*)d_ws + MINKEY_BYTE_OFF);
    unsigned* maxkeys = minkeys + NB;

    // init min/max keys: min -> 0xFFFFFFFF, max -> 0x00000000
    hipMemsetAsync(minkeys, 0xFF, NB * sizeof(unsigned), stream);
    hipMemsetAsync(maxkeys, 0x00, NB * sizeof(unsigned), stream);

    k_prep<<<NB * 8, 256, 0, stream>>>(pts, az, el, packed, minkeys, maxkeys);
    k_splat<<<NB * GROUPS, BTHREADS, 0, stream>>>(packed, minkeys, maxkeys, out);
}

// Round 5
// 134.431 us; speedup vs baseline: 1.1010x; 1.1010x over previous
//
#include <hip/hip_runtime.h>

#define IMG 224
#define HW (IMG * IMG)
#define HW4 (HW / 4)
#define NB 128
#define NPTS 16384

#define THREADS 1024
#define HALF_ROWS 112
#define TILE_FLOATS (HALF_ROWS * IMG)   // 25088 floats = 100352 B
#define PPT (NPTS / THREADS)            // 16 points per thread
#define NWAVES (THREADS / 64)           // 16
#define SMEM_FLOATS (TILE_FLOATS + 2 * NWAVES)

// One fused kernel. Grid = 256 blocks: block (b, h) owns image rows
// [h*112, (h+1)*112) of batch b. blockIdx = h*128 + b so both halves of a
// batch land on XCD b%8 (second read of the batch's points is L2-hot).
// Each block: load+transform ALL 16K points of batch b into REGISTERS
// (16 pts/thread), block-reduce z min/max, splat from registers into a
// 112x224 LDS tile (ds_add_f32), write exclusive region to 3 channels.
__global__ __launch_bounds__(THREADS) void k_render(const float* __restrict__ pts,
                                                    const float* __restrict__ az,
                                                    const float* __restrict__ el,
                                                    float* __restrict__ out) {
    extern __shared__ float smem[];
    float* tile = smem;                       // TILE_FLOATS
    float* wmin = smem + TILE_FLOATS;         // NWAVES
    float* wmax = wmin + NWAVES;              // NWAVES

    const int b = blockIdx.x & (NB - 1);
    const int h = blockIdx.x >> 7;            // 0 or 1
    const int y0 = h * HALF_ROWS;

    // Rotation matrix R = R_el @ R_az (wave-uniform).
    float sa, ca, se, ce;
    __sincosf(az[b], &sa, &ca);
    __sincosf(el[b], &se, &ce);
    const float r00 = ca,       r02 = sa;
    const float r10 = se * sa,  r11 = ce,  r12 = -se * ca;
    const float r20 = -ce * sa, r21 = se,  r22 = ce * ca;

    const float4* __restrict__ pb4 = (const float4*)(pts + (size_t)b * NPTS * 3);

    // ---- load + transform all points into registers; running z min/max ----
    float px[PPT], py[PPT], rz[PPT];
    float zmin = 1e30f, zmax = -1e30f;

#pragma unroll
    for (int it = 0; it < PPT / 4; ++it) {    // 4 iterations x 4 points
        const int t = it * THREADS + threadIdx.x;   // 4-point group index
        const float4 v0 = pb4[3 * t + 0];
        const float4 v1 = pb4[3 * t + 1];
        const float4 v2 = pb4[3 * t + 2];
        const float xs[4] = {v0.x, v0.w, v1.z, v2.y};
        const float ys[4] = {v0.y, v1.x, v1.w, v2.z};
        const float zs[4] = {v0.z, v1.y, v2.x, v2.w};
#pragma unroll
        for (int j = 0; j < 4; ++j) {
            const int k = it * 4 + j;
            const float x = xs[j], y = ys[j], z = zs[j];
            const float rx = r00 * x + r02 * z;
            const float ry = r10 * x + r11 * y + r12 * z;
            const float zz = r20 * x + r21 * y + r22 * z;
            px[k] = (rx + 1.0f) * (0.5f * IMG) - 0.5f;
            py[k] = (ry + 1.0f) * (0.5f * IMG) - 0.5f;
            rz[k] = zz;
            zmin = fminf(zmin, zz);
            zmax = fmaxf(zmax, zz);
        }
    }

    // ---- block reduce z min/max ----
    for (int m = 1; m < 64; m <<= 1) {
        zmin = fminf(zmin, __shfl_xor(zmin, m));
        zmax = fmaxf(zmax, __shfl_xor(zmax, m));
    }
    const int wid = threadIdx.x >> 6;
    if ((threadIdx.x & 63) == 0) { wmin[wid] = zmin; wmax[wid] = zmax; }

    // zero the tile while the reduce publishes
    for (int i = threadIdx.x; i < TILE_FLOATS; i += THREADS) tile[i] = 0.0f;
    __syncthreads();

#pragma unroll
    for (int w = 0; w < NWAVES; ++w) {
        zmin = fminf(zmin, wmin[w]);
        zmax = fmaxf(zmax, wmax[w]);
    }
    const float inv = 0.7f / (zmax - zmin + 1e-6f);

    // ---- splat from registers ----
#pragma unroll
    for (int k = 0; k < PPT; ++k) {
        const float p = px[k], q = py[k];
        const float fx1 = floorf(p);
        const float fy1 = floorf(q);
        // mask: px1>=0 && py1>=0 && px2<224 && py2<224  (px2 = px1+1)
        if (fx1 >= 0.0f && fy1 >= 0.0f && fx1 < (float)(IMG - 1) && fy1 < (float)(IMG - 1)) {
            const float feat = 0.3f + (rz[k] - zmin) * inv;
            const float wx2 = p - fx1, wx1 = 1.0f - wx2;
            const float wy2 = q - fy1, wy1 = 1.0f - wy2;
            const int ix = (int)fx1;
            const int r0 = (int)fy1 - y0;
            const int r1 = r0 + 1;
            if (r0 >= 0 && r0 < HALF_ROWS) {
                atomicAdd(&tile[r0 * IMG + ix],     wx1 * wy1 * feat);
                atomicAdd(&tile[r0 * IMG + ix + 1], wx2 * wy1 * feat);
            }
            if (r1 >= 0 && r1 < HALF_ROWS) {
                atomicAdd(&tile[r1 * IMG + ix],     wx1 * wy2 * feat);
                atomicAdd(&tile[r1 * IMG + ix + 1], wx2 * wy2 * feat);
            }
        }
    }

    __syncthreads();

    // ---- writeout: exclusive region -> 3 broadcast channels ----
    const float4* __restrict__ t4 = (const float4*)tile;
    float4* __restrict__ o4 = (float4*)(out + (size_t)b * 3 * HW + (size_t)y0 * IMG);
    for (int i = threadIdx.x; i < TILE_FLOATS / 4; i += THREADS) {
        const float4 v = t4[i];
        o4[i] = v;
        o4[i + HW4] = v;
        o4[i + 2 * HW4] = v;
    }
}

extern "C" void kernel_launch(void* const* d_in, const int* in_sizes, int n_in,
                              void* d_out, int out_size, void* d_ws, size_t ws_size,
                              hipStream_t stream) {
    const float* pts = (const float*)d_in[0];
    const float* az  = (const float*)d_in[1];
    const float* el  = (const float*)d_in[2];
    float* out = (float*)d_out;

    k_render<<<NB * 2, THREADS, SMEM_FLOATS * sizeof(float), stream>>>(pts, az, el, out);
}